// Round 14
// baseline (83.586 us; speedup 1.0000x reference)
//
#include <hip/hip_runtime.h>

// Factorial HMM forward (3 chains x 8 states = 512 states, M=4, T=65536).
// Probability-domain scaled forward recurrence, packed-f16 contractions:
// chain-0 in-lane pk_fma, chains 1/2 LDS-staged b128 exchange (stride-9
// padded second stage; zero bank conflicts). FOUR independent chunks/wave.
// R14 = R13 kernel with the grid fixed: R13 launched 256 blocks = 1/CU =
// 4 waves/CU max (grid-starved; occupancy 9.9%). Now NCHUNK 8192 / CLEN 8:
// 2048 waves / 512 blocks = 2 blocks/CU = 8 waves/CU launched, testing
// 4-stream ILP at proper residency. Tables pinned (R11); renorm-every-2;
// lgamma hoisted (2 loads); no prior (chunk 0 burns on t=0,1).

#define NCHUNK 8192
#define CLEN   8           // NCHUNK * CLEN == 65536
#define BURN   2
#define STEPS  (CLEN + BURN)   // 10: burn pair + 4 payload pairs
#define WPB    4           // waves per block (256 thr)
#define NWAVE  (NCHUNK / 4)
#define NBLK   (NWAVE / WPB)   // 512 blocks = 2/CU

// d_ws layout (bytes):
#define WS_T0   16         // int T0p[32]: [p*8+k] = (T0[2p][k], T0[2p+1][k]) f16x2
#define WS_T1   144        // int T1p[64]: [j*8+k] = dup(T1[j][k])
#define WS_T2   400        // int T2p[64]: [j*8+k] = dup(T2[j][k])
#define WS_LT   1024       // float Lt2[512][4]: log2(lamC[s][m]), s=r*64+j1*8+j2
#define WS_SL   9216       // float sl2[512]: sum_m lamC / ln2

typedef _Float16 h2 __attribute__((ext_vector_type(2)));
static __device__ __forceinline__ int h2i(h2 v) { return __builtin_bit_cast(int, v); }
static __device__ __forceinline__ h2 ih2(int v) { return __builtin_bit_cast(h2, v); }
static __device__ __forceinline__ h2 pkrtz(float a, float b) {
  return __builtin_bit_cast(h2, __builtin_amdgcn_cvt_pkrtz(a, b));
}
#define PIN(v) asm volatile("" : "+v"(v))

// Wave(64)-wide max via DPP butterfly on the VALU pipe (no DS ops).
static __device__ __forceinline__ float wave_max_dpp(float x) {
  int r = __builtin_bit_cast(int, x);
  auto mx = [](int a, int b) {
    return __builtin_bit_cast(
        int, fmaxf(__builtin_bit_cast(float, a), __builtin_bit_cast(float, b)));
  };
  int t;
  t = __builtin_amdgcn_update_dpp(r, r, 0x111, 0xf, 0xf, false); r = mx(r, t);
  t = __builtin_amdgcn_update_dpp(r, r, 0x112, 0xf, 0xf, false); r = mx(r, t);
  t = __builtin_amdgcn_update_dpp(r, r, 0x114, 0xf, 0xf, false); r = mx(r, t);
  t = __builtin_amdgcn_update_dpp(r, r, 0x118, 0xf, 0xf, false); r = mx(r, t);
  t = __builtin_amdgcn_update_dpp(r, r, 0x142, 0xa, 0xf, false); r = mx(r, t);
  t = __builtin_amdgcn_update_dpp(r, r, 0x143, 0xc, 0xf, false); r = mx(r, t);
  return __builtin_bit_cast(float, __builtin_amdgcn_readlane(r, 63));
}

__device__ __forceinline__ float wave_reduce_sum(float v) {
#pragma unroll
  for (int m = 32; m >= 1; m >>= 1) v += __shfl_xor(v, m, 64);
  return v;
}

static __device__ __forceinline__ float regmax8(const float (&e)[8]) {
  const float a = fmaxf(e[0], e[1]), b = fmaxf(e[2], e[3]);
  const float c = fmaxf(e[4], e[5]), d = fmaxf(e[6], e[7]);
  return fmaxf(fmaxf(a, b), fmaxf(c, d));
}

// Build transition/emission tables once (also zeroes the accumulator).
__global__ void setup_kernel(const float* __restrict__ lam0,
                             const float* __restrict__ lam1,
                             const float* __restrict__ lam2,
                             const float* __restrict__ logA0,
                             const float* __restrict__ logA1,
                             const float* __restrict__ logA2,
                             char* __restrict__ ws) {
  const int tid = threadIdx.x;
  if (tid == 0) *(double*)ws = 0.0;
  int* T0p = (int*)(ws + WS_T0);
  int* T1p = (int*)(ws + WS_T1);
  int* T2p = (int*)(ws + WS_T2);
  float* Lt2 = (float*)(ws + WS_LT);
  float* sl2 = (float*)(ws + WS_SL);

  if (tid < 8) {            // T0 column tid
    const int k = tid;
    float m = logA0[k];
    for (int j = 1; j < 8; ++j) m = fmaxf(m, logA0[j * 8 + k]);
    float p[8], s = 0.f;
    for (int j = 0; j < 8; ++j) { p[j] = __expf(logA0[j * 8 + k] - m); s += p[j]; }
    const float inv = 1.f / s;
    for (int pp = 0; pp < 4; ++pp)
      T0p[pp * 8 + k] = h2i(pkrtz(p[2 * pp] * inv, p[2 * pp + 1] * inv));
  } else if (tid < 16) {    // T1 column
    const int k = tid - 8;
    float m = logA1[k];
    for (int j = 1; j < 8; ++j) m = fmaxf(m, logA1[j * 8 + k]);
    float p[8], s = 0.f;
    for (int j = 0; j < 8; ++j) { p[j] = __expf(logA1[j * 8 + k] - m); s += p[j]; }
    const float inv = 1.f / s;
    for (int j = 0; j < 8; ++j) { float t = p[j] * inv; T1p[j * 8 + k] = h2i(pkrtz(t, t)); }
  } else if (tid < 24) {    // T2 column
    const int k = tid - 16;
    float m = logA2[k];
    for (int j = 1; j < 8; ++j) m = fmaxf(m, logA2[j * 8 + k]);
    float p[8], s = 0.f;
    for (int j = 0; j < 8; ++j) { p[j] = __expf(logA2[j * 8 + k] - m); s += p[j]; }
    const float inv = 1.f / s;
    for (int j = 0; j < 8; ++j) { float t = p[j] * inv; T2p[j * 8 + k] = h2i(pkrtz(t, t)); }
  }
  // all 512 threads: emission tables for state tid = r*64 + j1*8 + j2
  const int r = tid >> 6, j1 = (tid >> 3) & 7, j2 = tid & 7;
  float sl = 0.f;
  for (int m = 0; m < 4; ++m) {
    const float lam = lam0[r * 4 + m] + lam1[j1 * 4 + m] + lam2[j2 * 4 + m];
    Lt2[tid * 4 + m] = __log2f(lam);
    sl += lam;
  }
  sl2[tid] = sl * 1.44269504f;   // sumLam / ln2
}

__global__ __launch_bounds__(256, 1)
void hmm_fwd_chunk(const int* __restrict__ x,
                   const char* __restrict__ ws, double* __restrict__ accum)
{
  const int l = threadIdx.x & 63;                   // lane 0..63
  const int w = threadIdx.x >> 6;                   // wave 0..3
  const int gw = blockIdx.x * WPB + w;              // 0..NWAVE-1
  const int c0 = gw * 4;                            // chunks c0..c0+3
  const int j1 = l >> 3;
  const int j2 = l & 7;

  // per-stream staging: stage0 rows (j1<<3)|j2; stage1 rows j2*9+j1
  __shared__ int4 st0_0[WPB][64], st0_1[WPB][64], st0_2[WPB][64], st0_3[WPB][64];
  __shared__ int4 st1_0[WPB][72], st1_1[WPB][72], st1_2[WPB][72], st1_3[WPB][72];

  int4* b0_0 = st0_0[w]; int4* b0_1 = st0_1[w];
  int4* b0_2 = st0_2[w]; int4* b0_3 = st0_3[w];
  int4* b1_0 = st1_0[w]; int4* b1_1 = st1_1[w];
  int4* b1_2 = st1_2[w]; int4* b1_3 = st1_3[w];

  const int ts0 = c0 * CLEN;
  const int ts1 = ts0 + CLEN, ts2 = ts0 + 2 * CLEN, ts3 = ts0 + 3 * CLEN;

  // ---- lgamma side-sum for all four chunks: 2 coalesced loads ----
  // four chunks cover x ints [ts0*4, ts0*4 + 128)
  const float ctsum = wave_reduce_sum(
      lgammaf((float)x[ts0 * 4 + l] + 1.0f) +
      lgammaf((float)x[ts0 * 4 + 64 + l] + 1.0f));

  // ---- load tables from ws, then PIN in VGPRs (no rematerialization) ----
  int T0r[32];
  {
    const int4* p = (const int4*)(ws + WS_T0);
#pragma unroll
    for (int i = 0; i < 8; ++i) {
      const int4 g = p[i];
      T0r[4 * i] = g.x; T0r[4 * i + 1] = g.y; T0r[4 * i + 2] = g.z; T0r[4 * i + 3] = g.w;
    }
  }
  int T1r[8];
  {
    const int4* p = (const int4*)(ws + WS_T1) + j1 * 2;
    const int4 a = p[0], b = p[1];
    T1r[0] = a.x; T1r[1] = a.y; T1r[2] = a.z; T1r[3] = a.w;
    T1r[4] = b.x; T1r[5] = b.y; T1r[6] = b.z; T1r[7] = b.w;
  }
  int T2r[8];
  {
    const int4* p = (const int4*)(ws + WS_T2) + j2 * 2;
    const int4 a = p[0], b = p[1];
    T2r[0] = a.x; T2r[1] = a.y; T2r[2] = a.z; T2r[3] = a.w;
    T2r[4] = b.x; T2r[5] = b.y; T2r[6] = b.z; T2r[7] = b.w;
  }
  float Ltr[8][4], slr[8];
  {
    const float4* lt = (const float4*)(ws + WS_LT);
    const float* sl = (const float*)(ws + WS_SL);
#pragma unroll
    for (int r = 0; r < 8; ++r) {
      const float4 g = lt[r * 64 + l];
      Ltr[r][0] = g.x; Ltr[r][1] = g.y; Ltr[r][2] = g.z; Ltr[r][3] = g.w;
      slr[r] = sl[r * 64 + l];
    }
  }
#pragma unroll
  for (int i = 0; i < 32; ++i) PIN(T0r[i]);
#pragma unroll
  for (int i = 0; i < 8; ++i) { PIN(T1r[i]); PIN(T2r[i]); PIN(slr[i]); }
#pragma unroll
  for (int r = 0; r < 8; ++r)
#pragma unroll
    for (int m = 0; m < 4; ++m) PIN(Ltr[r][m]);

  // emission log2-prob excluding the wave-uniform lgamma term
  auto emis2 = [&](const int4 xi, float (&e)[8]) {
    const float xf0 = (float)xi.x, xf1 = (float)xi.y,
                xf2 = (float)xi.z, xf3 = (float)xi.w;
#pragma unroll
    for (int r = 0; r < 8; ++r) {
      float a = -slr[r];
      a = fmaf(xf0, Ltr[r][0], a);
      a = fmaf(xf1, Ltr[r][1], a);
      a = fmaf(xf2, Ltr[r][2], a);
      a = fmaf(xf3, Ltr[r][3], a);
      e[r] = a;
    }
  };
  auto chain0 = [&](const h2 (&vd)[8]) -> int4 {
    h2 q0 = ih2(T0r[0]) * vd[0], q1 = ih2(T0r[8]) * vd[0],
       q2 = ih2(T0r[16]) * vd[0], q3 = ih2(T0r[24]) * vd[0];
#pragma unroll
    for (int k = 1; k < 8; ++k) {
      q0 += ih2(T0r[k]) * vd[k];
      q1 += ih2(T0r[8 + k]) * vd[k];
      q2 += ih2(T0r[16 + k]) * vd[k];
      q3 += ih2(T0r[24 + k]) * vd[k];
    }
    return int4{h2i(q0), h2i(q1), h2i(q2), h2i(q3)};
  };
  // chain-1: read rows (k, j2) at stride 8; 8-lane broadcast, conflict-free
  auto mix1 = [&](const int4* buf) -> int4 {
    h2 a0{0, 0}, a1{0, 0}, a2{0, 0}, a3{0, 0};
#pragma unroll
    for (int g4 = 0; g4 < 2; ++g4) {
      int4 g[4];
#pragma unroll
      for (int k = 0; k < 4; ++k) g[k] = buf[((g4 * 4 + k) << 3) | j2];
#pragma unroll
      for (int k = 0; k < 4; ++k) {
        const h2 tk = ih2(T1r[g4 * 4 + k]);
        a0 += tk * ih2(g[k].x); a1 += tk * ih2(g[k].y);
        a2 += tk * ih2(g[k].z); a3 += tk * ih2(g[k].w);
      }
    }
    return int4{h2i(a0), h2i(a1), h2i(a2), h2i(a3)};
  };
  // chain-2: read rows k*9+j1 (stride-9 pad); conflict-free both directions
  auto mix2 = [&](const int4* buf) -> int4 {
    h2 a0{0, 0}, a1{0, 0}, a2{0, 0}, a3{0, 0};
#pragma unroll
    for (int g4 = 0; g4 < 2; ++g4) {
      int4 g[4];
#pragma unroll
      for (int k = 0; k < 4; ++k) g[k] = buf[(g4 * 4 + k) * 9 + j1];
#pragma unroll
      for (int k = 0; k < 4; ++k) {
        const h2 tk = ih2(T2r[g4 * 4 + k]);
        a0 += tk * ih2(g[k].x); a1 += tk * ih2(g[k].y);
        a2 += tk * ih2(g[k].z); a3 += tk * ih2(g[k].w);
      }
    }
    return int4{h2i(a0), h2i(a1), h2i(a2), h2i(a3)};
  };
  auto finishf = [&](const int4 av, const float (&e)[8], const float me,
                     float (&tl)[8]) {
    const int ai[4] = {av.x, av.y, av.z, av.w};
#pragma unroll
    for (int p = 0; p < 4; ++p) {
      const h2 ap = ih2(ai[p]);
      tl[2 * p]     = (float)ap.x * exp2f(e[2 * p] - me);
      tl[2 * p + 1] = (float)ap.y * exp2f(e[2 * p + 1] - me);
    }
  };

  h2 v0[8], v1[8], v2[8], v3[8];
#pragma unroll
  for (int r = 0; r < 8; ++r) {
    v0[r] = pkrtz(1.f, 1.f); v1[r] = pkrtz(1.f, 1.f);
    v2[r] = pkrtz(1.f, 1.f); v3[r] = pkrtz(1.f, 1.f);
  }
  float z0 = 0.f, z1 = 0.f, z2 = 0.f, z3 = 0.f;

  // read index for stream 0 (chunk 0 burns on t=0,1 instead of t<0)
  auto trd0 = [&](int u) { int t = ts0 - BURN + u; return t < 0 ? u : t; };

  int un = 0;   // prefetch cursor
  int4 xp0 = *reinterpret_cast<const int4*>(x + 4 * trd0(0));
  int4 xp1 = *reinterpret_cast<const int4*>(x + 4 * (ts1 - BURN));
  int4 xp2 = *reinterpret_cast<const int4*>(x + 4 * (ts2 - BURN));
  int4 xp3 = *reinterpret_cast<const int4*>(x + 4 * (ts3 - BURN));

  // one fused 4-stream step; RENORM/ACC are call-site literals
  auto step = [&](bool renorm, bool acc) {
    const int4 xi0 = xp0, xi1 = xp1, xi2 = xp2, xi3 = xp3;
    ++un;
    if (un < STEPS) {
      xp0 = *reinterpret_cast<const int4*>(x + 4 * trd0(un));
      xp1 = *reinterpret_cast<const int4*>(x + 4 * (ts1 - BURN + un));
      xp2 = *reinterpret_cast<const int4*>(x + 4 * (ts2 - BURN + un));
      xp3 = *reinterpret_cast<const int4*>(x + 4 * (ts3 - BURN + un));
    }

    float e0[8], e1[8], e2[8], e3[8];
    emis2(xi0, e0); emis2(xi1, e1); emis2(xi2, e2); emis2(xi3, e3);
    const float me0 = wave_max_dpp(regmax8(e0));
    const float me1 = wave_max_dpp(regmax8(e1));
    const float me2 = wave_max_dpp(regmax8(e2));
    const float me3 = wave_max_dpp(regmax8(e3));

    b0_0[l] = chain0(v0);
    b0_1[l] = chain0(v1);
    b0_2[l] = chain0(v2);
    b0_3[l] = chain0(v3);

    const int4 h0 = mix1(b0_0);
    const int4 h1 = mix1(b0_1);
    const int4 h2_ = mix1(b0_2);
    const int4 h3 = mix1(b0_3);
    b1_0[j2 * 9 + j1] = h0;
    b1_1[j2 * 9 + j1] = h1;
    b1_2[j2 * 9 + j1] = h2_;
    b1_3[j2 * 9 + j1] = h3;

    const int4 a0 = mix2(b1_0);
    const int4 a1 = mix2(b1_1);
    const int4 a2 = mix2(b1_2);
    const int4 a3 = mix2(b1_3);

    float tl0[8], tl1[8], tl2[8], tl3[8];
    finishf(a0, e0, me0, tl0);
    finishf(a1, e1, me1, tl1);
    finishf(a2, e2, me2, tl2);
    finishf(a3, e3, me3, tl3);

    if (renorm) {
      const float c0_ = wave_max_dpp(regmax8(tl0));
      const float c1_ = wave_max_dpp(regmax8(tl1));
      const float c2_ = wave_max_dpp(regmax8(tl2));
      const float c3_ = wave_max_dpp(regmax8(tl3));
      const float r0 = __builtin_amdgcn_rcpf(c0_);
      const float r1 = __builtin_amdgcn_rcpf(c1_);
      const float r2 = __builtin_amdgcn_rcpf(c2_);
      const float r3 = __builtin_amdgcn_rcpf(c3_);
#pragma unroll
      for (int r = 0; r < 8; ++r) {
        const float a = tl0[r] * r0, b = tl1[r] * r1;
        const float c = tl2[r] * r2, d = tl3[r] * r3;
        v0[r] = pkrtz(a, a); v1[r] = pkrtz(b, b);
        v2[r] = pkrtz(c, c); v3[r] = pkrtz(d, d);
      }
      if (acc) {
        z0 += __log2f(c0_); z1 += __log2f(c1_);
        z2 += __log2f(c2_); z3 += __log2f(c3_);
      }
    } else {
      // skip renorm: values <= 1, shrink only one step; folded into next c
#pragma unroll
      for (int r = 0; r < 8; ++r) {
        v0[r] = pkrtz(tl0[r], tl0[r]); v1[r] = pkrtz(tl1[r], tl1[r]);
        v2[r] = pkrtz(tl2[r], tl2[r]); v3[r] = pkrtz(tl3[r], tl3[r]);
      }
    }
    if (acc) { z0 += me0; z1 += me1; z2 += me2; z3 += me3; }
  };

  // burn pair (u=0,1): renorm at u=1, no accumulation
  step(false, false);
  step(true, false);
  // payload pairs (u=2..9)
#pragma unroll 1
  for (int uu = 0; uu < (STEPS - 2) / 2; ++uu) {
    step(false, true);
    step(true, true);
  }

  if (c0 + 3 == NCHUNK - 1) {
    float s = 0.f;
#pragma unroll
    for (int r = 0; r < 8; ++r) s += (float)v3[r].x;
    s = wave_reduce_sum(s);
    z3 += __log2f(s);
  }

  if (l == 0)
    atomicAdd(accum,
              ((double)z0 + (double)z1 + (double)z2 + (double)z3) *
                      0.6931471805599453 -
                  (double)ctsum);
}

__global__ void finalize_kernel(const double* __restrict__ acc,
                                float* __restrict__ out) {
  if (threadIdx.x == 0) out[0] = (float)(*acc);
}

extern "C" void kernel_launch(void* const* d_in, const int* in_sizes, int n_in,
                              void* d_out, int out_size, void* d_ws, size_t ws_size,
                              hipStream_t stream) {
  const int*   x     = (const int*)d_in[0];
  const float* lam0  = (const float*)d_in[1];
  const float* lam1  = (const float*)d_in[2];
  const float* lam2  = (const float*)d_in[3];
  const float* logA0 = (const float*)d_in[4];
  const float* logA1 = (const float*)d_in[5];
  const float* logA2 = (const float*)d_in[6];
  float* out = (float*)d_out;

  setup_kernel<<<1, 512, 0, stream>>>(lam0, lam1, lam2, logA0, logA1, logA2,
                                      (char*)d_ws);
  hmm_fwd_chunk<<<NBLK, 256, 0, stream>>>(x, (const char*)d_ws, (double*)d_ws);
  finalize_kernel<<<1, 64, 0, stream>>>((const double*)d_ws, out);
}

// Round 15
// 62.868 us; speedup vs baseline: 1.3296x; 1.3296x over previous
//
#include <hip/hip_runtime.h>

// Factorial HMM forward (3 chains x 8 states = 512 states, M=4, T=65536).
// Probability-domain scaled forward recurrence, packed-f16 contractions:
// chain-0 in-lane pk_fma, chains 1/2 LDS-staged b128 exchange (stride-9
// padded second stage; zero bank conflicts). Two independent chunks/wave.
// R15 = R11 (best: 60.4us) + explicit software pipelining: every DS read
// burst has the OTHER stream's pure-VALU work (emis+DPP max / exp2 factors)
// placed between issue and consume, so DS latency is covered in program
// order instead of hoped-for compiler reordering. BURN 2->1 (17 steps).

#define NCHUNK 4096
#define CLEN   16          // NCHUNK * CLEN == 65536
#define BURN   1
#define STEPS  (CLEN + BURN)   // 17: burn step + 8 payload pairs
#define WPB    4           // waves per block (256 thr)
#define NWAVE  (NCHUNK / 2)
#define NBLK   (NWAVE / WPB)

// d_ws layout (bytes):
#define WS_T0   16         // int T0p[32]: [p*8+k] = (T0[2p][k], T0[2p+1][k]) f16x2
#define WS_T1   144        // int T1p[64]: [j*8+k] = dup(T1[j][k])
#define WS_T2   400        // int T2p[64]: [j*8+k] = dup(T2[j][k])
#define WS_LT   1024       // float Lt2[512][4]: log2(lamC[s][m]), s=r*64+j1*8+j2
#define WS_SL   9216       // float sl2[512]: sum_m lamC / ln2

typedef _Float16 h2 __attribute__((ext_vector_type(2)));
static __device__ __forceinline__ int h2i(h2 v) { return __builtin_bit_cast(int, v); }
static __device__ __forceinline__ h2 ih2(int v) { return __builtin_bit_cast(h2, v); }
static __device__ __forceinline__ h2 pkrtz(float a, float b) {
  return __builtin_bit_cast(h2, __builtin_amdgcn_cvt_pkrtz(a, b));
}
#define PIN(v) asm volatile("" : "+v"(v))

// Wave(64)-wide max via DPP butterfly on the VALU pipe (no DS ops).
static __device__ __forceinline__ float wave_max_dpp(float x) {
  int r = __builtin_bit_cast(int, x);
  auto mx = [](int a, int b) {
    return __builtin_bit_cast(
        int, fmaxf(__builtin_bit_cast(float, a), __builtin_bit_cast(float, b)));
  };
  int t;
  t = __builtin_amdgcn_update_dpp(r, r, 0x111, 0xf, 0xf, false); r = mx(r, t);
  t = __builtin_amdgcn_update_dpp(r, r, 0x112, 0xf, 0xf, false); r = mx(r, t);
  t = __builtin_amdgcn_update_dpp(r, r, 0x114, 0xf, 0xf, false); r = mx(r, t);
  t = __builtin_amdgcn_update_dpp(r, r, 0x118, 0xf, 0xf, false); r = mx(r, t);
  t = __builtin_amdgcn_update_dpp(r, r, 0x142, 0xa, 0xf, false); r = mx(r, t);
  t = __builtin_amdgcn_update_dpp(r, r, 0x143, 0xc, 0xf, false); r = mx(r, t);
  return __builtin_bit_cast(float, __builtin_amdgcn_readlane(r, 63));
}

__device__ __forceinline__ float wave_reduce_sum(float v) {
#pragma unroll
  for (int m = 32; m >= 1; m >>= 1) v += __shfl_xor(v, m, 64);
  return v;
}

static __device__ __forceinline__ float regmax8(const float (&e)[8]) {
  const float a = fmaxf(e[0], e[1]), b = fmaxf(e[2], e[3]);
  const float c = fmaxf(e[4], e[5]), d = fmaxf(e[6], e[7]);
  return fmaxf(fmaxf(a, b), fmaxf(c, d));
}

// Build transition/emission tables once (also zeroes the accumulator).
__global__ void setup_kernel(const float* __restrict__ lam0,
                             const float* __restrict__ lam1,
                             const float* __restrict__ lam2,
                             const float* __restrict__ logA0,
                             const float* __restrict__ logA1,
                             const float* __restrict__ logA2,
                             char* __restrict__ ws) {
  const int tid = threadIdx.x;
  if (tid == 0) *(double*)ws = 0.0;
  int* T0p = (int*)(ws + WS_T0);
  int* T1p = (int*)(ws + WS_T1);
  int* T2p = (int*)(ws + WS_T2);
  float* Lt2 = (float*)(ws + WS_LT);
  float* sl2 = (float*)(ws + WS_SL);

  if (tid < 8) {            // T0 column tid
    const int k = tid;
    float m = logA0[k];
    for (int j = 1; j < 8; ++j) m = fmaxf(m, logA0[j * 8 + k]);
    float p[8], s = 0.f;
    for (int j = 0; j < 8; ++j) { p[j] = __expf(logA0[j * 8 + k] - m); s += p[j]; }
    const float inv = 1.f / s;
    for (int pp = 0; pp < 4; ++pp)
      T0p[pp * 8 + k] = h2i(pkrtz(p[2 * pp] * inv, p[2 * pp + 1] * inv));
  } else if (tid < 16) {    // T1 column
    const int k = tid - 8;
    float m = logA1[k];
    for (int j = 1; j < 8; ++j) m = fmaxf(m, logA1[j * 8 + k]);
    float p[8], s = 0.f;
    for (int j = 0; j < 8; ++j) { p[j] = __expf(logA1[j * 8 + k] - m); s += p[j]; }
    const float inv = 1.f / s;
    for (int j = 0; j < 8; ++j) { float t = p[j] * inv; T1p[j * 8 + k] = h2i(pkrtz(t, t)); }
  } else if (tid < 24) {    // T2 column
    const int k = tid - 16;
    float m = logA2[k];
    for (int j = 1; j < 8; ++j) m = fmaxf(m, logA2[j * 8 + k]);
    float p[8], s = 0.f;
    for (int j = 0; j < 8; ++j) { p[j] = __expf(logA2[j * 8 + k] - m); s += p[j]; }
    const float inv = 1.f / s;
    for (int j = 0; j < 8; ++j) { float t = p[j] * inv; T2p[j * 8 + k] = h2i(pkrtz(t, t)); }
  }
  // all 512 threads: emission tables for state tid = r*64 + j1*8 + j2
  const int r = tid >> 6, j1 = (tid >> 3) & 7, j2 = tid & 7;
  float sl = 0.f;
  for (int m = 0; m < 4; ++m) {
    const float lam = lam0[r * 4 + m] + lam1[j1 * 4 + m] + lam2[j2 * 4 + m];
    Lt2[tid * 4 + m] = __log2f(lam);
    sl += lam;
  }
  sl2[tid] = sl * 1.44269504f;   // sumLam / ln2
}

__global__ __launch_bounds__(256, 1)
void hmm_fwd_chunk(const int* __restrict__ x,
                   const char* __restrict__ ws, double* __restrict__ accum)
{
  const int l = threadIdx.x & 63;                   // lane 0..63
  const int w = threadIdx.x >> 6;                   // wave 0..3
  const int gw = blockIdx.x * WPB + w;              // 0..NWAVE-1
  const int cA = gw * 2, cB = cA + 1;               // this wave's two chunks
  const int j1 = l >> 3;
  const int j2 = l & 7;

  __shared__ int4 sA0[WPB][64], sB0[WPB][64];   // chain-1 staging, rows (j1<<3)|j2
  __shared__ int4 sA1[WPB][72], sB1[WPB][72];   // chain-2 staging, rows j2*9+j1

  int4* bA0 = sA0[w]; int4* bB0 = sB0[w];
  int4* bA1 = sA1[w]; int4* bB1 = sB1[w];

  const int tsA = cA * CLEN, tsB = cB * CLEN;

  // ---- lgamma side-sum for both chunks' payload: two coalesced loads ----
  const float ctsum = wave_reduce_sum(
      lgammaf((float)x[tsA * 4 + l] + 1.0f) +
      lgammaf((float)x[tsA * 4 + 64 + l] + 1.0f));

  // ---- load tables from ws, then PIN in VGPRs (no rematerialization) ----
  int T0r[32];
  {
    const int4* p = (const int4*)(ws + WS_T0);
#pragma unroll
    for (int i = 0; i < 8; ++i) {
      const int4 g = p[i];
      T0r[4 * i] = g.x; T0r[4 * i + 1] = g.y; T0r[4 * i + 2] = g.z; T0r[4 * i + 3] = g.w;
    }
  }
  int T1r[8];
  {
    const int4* p = (const int4*)(ws + WS_T1) + j1 * 2;
    const int4 a = p[0], b = p[1];
    T1r[0] = a.x; T1r[1] = a.y; T1r[2] = a.z; T1r[3] = a.w;
    T1r[4] = b.x; T1r[5] = b.y; T1r[6] = b.z; T1r[7] = b.w;
  }
  int T2r[8];
  {
    const int4* p = (const int4*)(ws + WS_T2) + j2 * 2;
    const int4 a = p[0], b = p[1];
    T2r[0] = a.x; T2r[1] = a.y; T2r[2] = a.z; T2r[3] = a.w;
    T2r[4] = b.x; T2r[5] = b.y; T2r[6] = b.z; T2r[7] = b.w;
  }
  float Ltr[8][4], slr[8];
  {
    const float4* lt = (const float4*)(ws + WS_LT);
    const float* sl = (const float*)(ws + WS_SL);
#pragma unroll
    for (int r = 0; r < 8; ++r) {
      const float4 g = lt[r * 64 + l];
      Ltr[r][0] = g.x; Ltr[r][1] = g.y; Ltr[r][2] = g.z; Ltr[r][3] = g.w;
      slr[r] = sl[r * 64 + l];
    }
  }
#pragma unroll
  for (int i = 0; i < 32; ++i) PIN(T0r[i]);
#pragma unroll
  for (int i = 0; i < 8; ++i) { PIN(T1r[i]); PIN(T2r[i]); PIN(slr[i]); }
#pragma unroll
  for (int r = 0; r < 8; ++r)
#pragma unroll
    for (int m = 0; m < 4; ++m) PIN(Ltr[r][m]);

  // emission log2-prob excluding the wave-uniform lgamma term
  auto emis2 = [&](const int4 xi, float (&e)[8]) {
    const float xf0 = (float)xi.x, xf1 = (float)xi.y,
                xf2 = (float)xi.z, xf3 = (float)xi.w;
#pragma unroll
    for (int r = 0; r < 8; ++r) {
      float a = -slr[r];
      a = fmaf(xf0, Ltr[r][0], a);
      a = fmaf(xf1, Ltr[r][1], a);
      a = fmaf(xf2, Ltr[r][2], a);
      a = fmaf(xf3, Ltr[r][3], a);
      e[r] = a;
    }
  };
  auto chain0 = [&](const h2 (&vd)[8]) -> int4 {
    h2 q0 = ih2(T0r[0]) * vd[0], q1 = ih2(T0r[8]) * vd[0],
       q2 = ih2(T0r[16]) * vd[0], q3 = ih2(T0r[24]) * vd[0];
#pragma unroll
    for (int k = 1; k < 8; ++k) {
      q0 += ih2(T0r[k]) * vd[k];
      q1 += ih2(T0r[8 + k]) * vd[k];
      q2 += ih2(T0r[16 + k]) * vd[k];
      q3 += ih2(T0r[24 + k]) * vd[k];
    }
    return int4{h2i(q0), h2i(q1), h2i(q2), h2i(q3)};
  };
  // accumulate 8 staged rows with weights Tw -> one int4 of 4 h2
  auto accum8 = [&](const int4 (&g)[8], const int* Tw) -> int4 {
    h2 a0{0, 0}, a1{0, 0}, a2{0, 0}, a3{0, 0};
#pragma unroll
    for (int k = 0; k < 8; ++k) {
      const h2 tk = ih2(Tw[k]);
      a0 += tk * ih2(g[k].x); a1 += tk * ih2(g[k].y);
      a2 += tk * ih2(g[k].z); a3 += tk * ih2(g[k].w);
    }
    return int4{h2i(a0), h2i(a1), h2i(a2), h2i(a3)};
  };

  h2 vA[8], vB[8];
#pragma unroll
  for (int r = 0; r < 8; ++r) { vA[r] = pkrtz(1.f, 1.f); vB[r] = pkrtz(1.f, 1.f); }
  float zA = 0.f, zB = 0.f;

  // read index for step u (chunk 0 burns on t=0 instead of t<0)
  auto trdA = [&](int u) { int t = tsA - BURN + u; return t < 0 ? 0 : t; };

  int un = 0;   // prefetch cursor
  int4 xA = *reinterpret_cast<const int4*>(x + 4 * trdA(0));
  int4 xB = *reinterpret_cast<const int4*>(x + 4 * (tsB - BURN));

  // one fused A+B step, software-pipelined: each DS read burst is covered
  // by the OTHER stream's pure-VALU work in program order.
  auto step = [&](bool renorm, bool acc) {
    const int4 xiA = xA, xiB = xB;
    ++un;
    if (un < STEPS) {
      xA = *reinterpret_cast<const int4*>(x + 4 * trdA(un));
      xB = *reinterpret_cast<const int4*>(x + 4 * (tsB - BURN + un));
    }

    // stage-0: chain0 (pure VALU) + both stage-0 writes
    bA0[l] = chain0(vA);
    bB0[l] = chain0(vB);

    // A stage-1 reads in flight ...
    int4 g[8];
#pragma unroll
    for (int k = 0; k < 8; ++k) g[k] = bA0[(k << 3) | j2];
    // ... covered by B's emission + DPP max
    float eB[8];
    emis2(xiB, eB);
    const float meB = wave_max_dpp(regmax8(eB));
    // consume A stage-1, write A stage-2
    const int4 hA = accum8(g, T1r);
    bA1[j2 * 9 + j1] = hA;

    // B stage-1 reads in flight ...
#pragma unroll
    for (int k = 0; k < 8; ++k) g[k] = bB0[(k << 3) | j2];
    // ... covered by A's emission + DPP max
    float eA[8];
    emis2(xiA, eA);
    const float meA = wave_max_dpp(regmax8(eA));
    // consume B stage-1, write B stage-2
    const int4 hB = accum8(g, T1r);
    bB1[j2 * 9 + j1] = hB;

    // A stage-2 reads in flight ...
    int4 g2[8];
#pragma unroll
    for (int k = 0; k < 8; ++k) g2[k] = bA1[k * 9 + j1];
    // ... covered by B's exp2 factors
    float fB[8];
#pragma unroll
    for (int r = 0; r < 8; ++r) fB[r] = exp2f(eB[r] - meB);
    const int4 aA = accum8(g2, T2r);

    // B stage-2 reads in flight ...
#pragma unroll
    for (int k = 0; k < 8; ++k) g2[k] = bB1[k * 9 + j1];
    // ... covered by A's exp2 factors
    float fA[8];
#pragma unroll
    for (int r = 0; r < 8; ++r) fA[r] = exp2f(eA[r] - meA);
    const int4 aB = accum8(g2, T2r);

    // finish: emission multiply
    float tlA[8], tlB[8];
    {
      const int aiA[4] = {aA.x, aA.y, aA.z, aA.w};
      const int aiB[4] = {aB.x, aB.y, aB.z, aB.w};
#pragma unroll
      for (int p = 0; p < 4; ++p) {
        const h2 pa = ih2(aiA[p]), pb = ih2(aiB[p]);
        tlA[2 * p]     = (float)pa.x * fA[2 * p];
        tlA[2 * p + 1] = (float)pa.y * fA[2 * p + 1];
        tlB[2 * p]     = (float)pb.x * fB[2 * p];
        tlB[2 * p + 1] = (float)pb.y * fB[2 * p + 1];
      }
    }

    if (renorm) {
      const float cA_ = wave_max_dpp(regmax8(tlA));
      const float cB_ = wave_max_dpp(regmax8(tlB));
      const float rA = __builtin_amdgcn_rcpf(cA_);
      const float rB = __builtin_amdgcn_rcpf(cB_);
#pragma unroll
      for (int r = 0; r < 8; ++r) {
        const float va = tlA[r] * rA, vb = tlB[r] * rB;
        vA[r] = pkrtz(va, va);
        vB[r] = pkrtz(vb, vb);
      }
      if (acc) { zA += __log2f(cA_); zB += __log2f(cB_); }
    } else {
      // skip renorm: values <= 1, shrink only one step; folded into next c
#pragma unroll
      for (int r = 0; r < 8; ++r) {
        vA[r] = pkrtz(tlA[r], tlA[r]);
        vB[r] = pkrtz(tlB[r], tlB[r]);
      }
    }
    if (acc) { zA += meA; zB += meB; }
  };

  // burn step (u=0): renorm, no accumulation
  step(true, false);
  // payload pairs (u=1..16)
#pragma unroll 1
  for (int uu = 0; uu < (STEPS - 1) / 2; ++uu) {
    step(false, true);
    step(true, true);
  }

  if (cB == NCHUNK - 1) {
    float s = 0.f;
#pragma unroll
    for (int r = 0; r < 8; ++r) s += (float)vB[r].x;
    s = wave_reduce_sum(s);
    zB += __log2f(s);
  }

  if (l == 0)
    atomicAdd(accum, ((double)zA + (double)zB) * 0.6931471805599453
                       - (double)ctsum);
}

__global__ void finalize_kernel(const double* __restrict__ acc,
                                float* __restrict__ out) {
  if (threadIdx.x == 0) out[0] = (float)(*acc);
}

extern "C" void kernel_launch(void* const* d_in, const int* in_sizes, int n_in,
                              void* d_out, int out_size, void* d_ws, size_t ws_size,
                              hipStream_t stream) {
  const int*   x     = (const int*)d_in[0];
  const float* lam0  = (const float*)d_in[1];
  const float* lam1  = (const float*)d_in[2];
  const float* lam2  = (const float*)d_in[3];
  const float* logA0 = (const float*)d_in[4];
  const float* logA1 = (const float*)d_in[5];
  const float* logA2 = (const float*)d_in[6];
  float* out = (float*)d_out;

  setup_kernel<<<1, 512, 0, stream>>>(lam0, lam1, lam2, logA0, logA1, logA2,
                                      (char*)d_ws);
  hmm_fwd_chunk<<<NBLK, 256, 0, stream>>>(x, (const char*)d_ws, (double*)d_ws);
  finalize_kernel<<<1, 64, 0, stream>>>((const double*)d_ws, out);
}